// Round 2
// baseline (26971.609 us; speedup 1.0000x reference)
//
#include <hip/hip_runtime.h>
#include <math.h>

// VQ quantizer, fp32-SEMANTICS-EXACT argmin:
//   dist(r,c) = fl32( fl32(r2_r + e2_c) - 2 * dot_fma_chain(r,c) )
// dot = sequential __fmaf_rn chain over k=0..255 (matches BLAS sgemm microkernel).
// argmin = first-min-wins (strict <, ascending c, lexicographic merge).
// r2/e2 computed f64->f32 (argmin invariant under per-row quantum translation).
// Outputs (float32 flat): [loss | quantized(8192*256) | indices(8192 as float)]

#define NROWS 8192
#define DDIM  256
#define KCW   8192
#define CPARTS 32              // c-split: 256 candidates per wave
#define CRANGE (KCW / CPARTS)  // 256
#define RS    128              // rows per wave
#define NRC   (NROWS / RS)     // 64

// ws layout (bytes): e2f f32[8192] @0 | r2f f32[8192] @32768 |
//   Part[8192][32] @65536 (2MB) | fidx int[8192] @2162688 |
//   lpart double[2048] @2195456 ; total 2,211,840 B

struct Part { float m; int i; };

__global__ __launch_bounds__(256) void k_prep(const float* __restrict__ z,
                                              const float* __restrict__ cb,
                                              float* __restrict__ r2f,
                                              float* __restrict__ e2f) {
  int t = threadIdx.x, w = t >> 6, lane = t & 63;
  int wid = blockIdx.x * 4 + w;  // 0..16383: first 8192 = z rows, rest = cb rows
  const float* src = (wid < NROWS) ? (z + (size_t)wid * DDIM)
                                   : (cb + (size_t)(wid - NROWS) * DDIM);
  float4 v = *reinterpret_cast<const float4*>(src + lane * 4);
  double d = (double)v.x * v.x + (double)v.y * v.y + (double)v.z * v.z + (double)v.w * v.w;
#pragma unroll
  for (int off = 1; off < 64; off <<= 1) d += __shfl_xor(d, off);
  if (lane == 0) {
    if (wid < NROWS) r2f[wid] = (float)d;
    else             e2f[wid - NROWS] = (float)d;
  }
}

// Wave: 64 lanes = 64 candidates (one c-tile), 4 c-tiles sequential, 128 rows.
// Each lane runs the sequential k-chain for its c against 16-row blocks whose
// x-values arrive as wave-uniform (broadcast) float4 loads.
__global__ __launch_bounds__(256) void k_argmin(const float* __restrict__ z,
                                                const float* __restrict__ cb,
                                                const float* __restrict__ r2f,
                                                const float* __restrict__ e2f,
                                                Part* __restrict__ part) {
  int t = threadIdx.x, w = t >> 6, lane = t & 63;
  int wid = blockIdx.x * 4 + w;     // 0..2047
  int rc = wid >> 5;                // / CPARTS -> 0..63
  int cp = wid & (CPARTS - 1);
  int row0 = rc * RS;
  int cbase = cp * CRANGE;

  for (int rb = 0; rb < 8; ++rb) {  // 8 x 16 rows
    float m[16]; int mi[16];
#pragma unroll
    for (int r = 0; r < 16; ++r) { m[r] = INFINITY; mi[r] = 0; }

#pragma unroll
    for (int ct = 0; ct < 4; ++ct) {
      int c = cbase + ct * 64 + lane;
      const float* ep = cb + (size_t)c * DDIM;
      float e2c = e2f[c];
      float acc[16];
#pragma unroll
      for (int r = 0; r < 16; ++r) acc[r] = 0.f;

#pragma unroll
      for (int kb = 0; kb < 4; ++kb) {
        float4 er[16];                       // lane's codeword slice (64 floats)
#pragma unroll
        for (int j = 0; j < 16; ++j)
          er[j] = *reinterpret_cast<const float4*>(ep + kb * 64 + j * 4);
#pragma unroll
        for (int r = 0; r < 16; ++r) {
          const float* xp = z + (size_t)(row0 + rb * 16 + r) * DDIM + kb * 64;
#pragma unroll
          for (int j = 0; j < 16; ++j) {     // k ascending: exact chain order
            float4 x4 = *reinterpret_cast<const float4*>(xp + j * 4);
            acc[r] = __fmaf_rn(x4.x, er[j].x, acc[r]);
            acc[r] = __fmaf_rn(x4.y, er[j].y, acc[r]);
            acc[r] = __fmaf_rn(x4.z, er[j].z, acc[r]);
            acc[r] = __fmaf_rn(x4.w, er[j].w, acc[r]);
          }
        }
      }
#pragma unroll
      for (int r = 0; r < 16; ++r) {
        float r2v = r2f[row0 + rb * 16 + r];                 // broadcast load
        float s = __fsub_rn(__fadd_rn(r2v, e2c), __fmul_rn(2.0f, acc[r]));
        if (s < m[r]) { m[r] = s; mi[r] = c; }   // c ascending per lane -> first-wins
      }
    }
    // cross-lane lexicographic (score, index) argmin: first-min-wins semantics
#pragma unroll
    for (int r = 0; r < 16; ++r) {
      float s = m[r]; int i = mi[r];
#pragma unroll
      for (int off = 1; off < 64; off <<= 1) {
        float os = __shfl_xor(s, off); int oi = __shfl_xor(i, off);
        if (os < s || (os == s && oi < i)) { s = os; i = oi; }
      }
      if (lane == 0) {
        Part p; p.m = s; p.i = i;
        part[(size_t)(row0 + rb * 16 + r) * CPARTS + cp] = p;
      }
    }
  }
}

__global__ __launch_bounds__(256) void k_merge(const Part* __restrict__ part,
                                               int* __restrict__ fidx,
                                               float* __restrict__ out_idx) {
  int row = blockIdx.x * 256 + threadIdx.x;
  float m = INFINITY; int mi = 0x7fffffff;
  for (int p = 0; p < CPARTS; ++p) {          // ascending c ranges
    Part pp = part[(size_t)row * CPARTS + p];
    if (pp.m < m || (pp.m == m && pp.i < mi)) { m = pp.m; mi = pp.i; }
  }
  fidx[row] = mi;
  out_idx[row] = (float)mi;
}

__global__ __launch_bounds__(256) void k_gather(const float* __restrict__ z,
                                                const float* __restrict__ cb,
                                                const int* __restrict__ fidx,
                                                float* __restrict__ out_q,
                                                double* __restrict__ lpart) {
  __shared__ double red[4];
  int t = threadIdx.x;
  int w = t >> 6, lane = t & 63;
  int row = blockIdx.x * 4 + w;
  int idx = fidx[row];
  float4 q = *reinterpret_cast<const float4*>(cb + (size_t)idx * DDIM + lane * 4);
  float4 x = *reinterpret_cast<const float4*>(z + (size_t)row * DDIM + lane * 4);
  float* o = out_q + (size_t)row * DDIM + lane * 4;  // out+1 base: scalar stores
  o[0] = q.x; o[1] = q.y; o[2] = q.z; o[3] = q.w;
  float dx = q.x - x.x, dy = q.y - x.y, dz = q.z - x.z, dw = q.w - x.w;
  double s = (double)dx * dx + (double)dy * dy + (double)dz * dz + (double)dw * dw;
#pragma unroll
  for (int off = 1; off < 64; off <<= 1) s += __shfl_xor(s, off);
  if (lane == 0) red[w] = s;
  __syncthreads();
  if (t == 0) lpart[blockIdx.x] = (red[0] + red[1]) + (red[2] + red[3]);
}

__global__ __launch_bounds__(256) void k_loss(const double* __restrict__ lpart,
                                              float* __restrict__ out0) {
  __shared__ double red[256];
  int t = threadIdx.x;
  double s = 0.0;
  for (int j = t; j < 2048; j += 256) s += lpart[j];
  red[t] = s;
  __syncthreads();
  for (int off = 128; off > 0; off >>= 1) {
    if (t < off) red[t] += red[t + off];
    __syncthreads();
  }
  if (t == 0) out0[0] = (float)(1.25 * red[0] / (double)((size_t)NROWS * DDIM));
}

extern "C" void kernel_launch(void* const* d_in, const int* in_sizes, int n_in,
                              void* d_out, int out_size, void* d_ws, size_t ws_size,
                              hipStream_t stream) {
  const float* z  = (const float*)d_in[0];   // [16,512,256] flat
  const float* cb = (const float*)d_in[1];   // [8192,256]
  float* out = (float*)d_out;
  char* ws = (char*)d_ws;

  float*  e2f   = (float*)(ws);
  float*  r2f   = (float*)(ws + 32768);
  Part*   part  = (Part*)(ws + 65536);
  int*    fidx  = (int*)(ws + 65536 + (size_t)NROWS * CPARTS * sizeof(Part));
  double* lpart = (double*)(ws + 65536 + (size_t)NROWS * CPARTS * sizeof(Part) + 32768);

  float* out_q   = out + 1;
  float* out_idx = out + 1 + (size_t)NROWS * DDIM;

  k_prep  <<<(2 * NROWS) / 4, 256, 0, stream>>>(z, cb, r2f, e2f);
  k_argmin<<<(NRC * CPARTS) / 4, 256, 0, stream>>>(z, cb, r2f, e2f, part);
  k_merge <<<NROWS / 256, 256, 0, stream>>>(part, fidx, out_idx);
  k_gather<<<NROWS / 4, 256, 0, stream>>>(z, cb, fidx, out_q, lpart);
  k_loss  <<<1, 256, 0, stream>>>(lpart, out);
}

// Round 4
// 493.235 us; speedup vs baseline: 54.6831x; 54.6831x over previous
//
#include <hip/hip_runtime.h>
#include <math.h>

// VQ quantizer — EXACT fp32-semantics argmin via register-blocked fp32 GEMM.
//   dist(r,c) = fl32( fl32(r2_r + e2_c) - 2 * fma_chain_k0..255(x_r . e_c) )
//   (chain semantics validated bit-exact vs np in round 2)
// Fused argmin: per-row lex-min(s, idx) packed into u64, atomicMin.
// Outputs (float32 flat): [loss | quantized(8192*256) | indices(8192 as float)]

#define NROWS 8192
#define DDIM  256
#define LDP   36   // padded LDS row stride (floats); 144B: 16B-aligned, conflict-free

__device__ inline unsigned fmap(float f) {
  unsigned b = __float_as_uint(f);
  return (b & 0x80000000u) ? ~b : (b | 0x80000000u);
}

__global__ __launch_bounds__(256) void k_prep(const float* __restrict__ z,
                                              const float* __restrict__ cb,
                                              float* __restrict__ r2f,
                                              float* __restrict__ e2f) {
  int t = threadIdx.x, w = t >> 6, lane = t & 63;
  int wid = blockIdx.x * 4 + w;  // 0..16383: first 8192 = z rows, rest = cb rows
  const float* src = (wid < NROWS) ? (z + (size_t)wid * DDIM)
                                   : (cb + (size_t)(wid - NROWS) * DDIM);
  float4 v = *reinterpret_cast<const float4*>(src + lane * 4);
  double d = (double)v.x * v.x + (double)v.y * v.y + (double)v.z * v.z + (double)v.w * v.w;
#pragma unroll
  for (int off = 1; off < 64; off <<= 1) d += __shfl_xor(d, off);
  if (lane == 0) {
    if (wid < NROWS) r2f[wid] = (float)d;
    else             e2f[wid - NROWS] = (float)d;
  }
}

// 128x128 tile, 256 threads, per-thread 8 rows x 8 cols (strided by 16).
// K never split: each acc[i][j] accumulates k=0..255 sequentially -> exact chain.
__global__ __launch_bounds__(256, 2) void k_exact(const float* __restrict__ z,
                                                  const float* __restrict__ cb,
                                                  const float* __restrict__ r2f,
                                                  const float* __restrict__ e2f,
                                                  unsigned long long* __restrict__ packed) {
  __shared__ float Xs[128 * LDP];
  __shared__ float Es[128 * LDP];
  int tid = threadIdx.x;
  int ct = tid & 15, rg = tid >> 4;
  int mt = blockIdx.x >> 6, nt = blockIdx.x & 63;
  int R0 = mt * 128, C0 = nt * 128;

  float acc[8][8];
#pragma unroll
  for (int i = 0; i < 8; ++i)
#pragma unroll
    for (int j = 0; j < 8; ++j) acc[i][j] = 0.f;

  for (int kc = 0; kc < 8; ++kc) {          // K chunks of 32, ascending
    int k0 = kc * 32;
#pragma unroll
    for (int q = 0; q < 4; ++q) {           // stage X (16KB) + E (16KB)
      int id = q * 256 + tid;               // 0..1023
      int row = id >> 3, kq = id & 7;
      *reinterpret_cast<float4*>(&Xs[row * LDP + kq * 4]) =
          *reinterpret_cast<const float4*>(&z[(size_t)(R0 + row) * DDIM + k0 + kq * 4]);
      *reinterpret_cast<float4*>(&Es[row * LDP + kq * 4]) =
          *reinterpret_cast<const float4*>(&cb[(size_t)(C0 + row) * DDIM + k0 + kq * 4]);
    }
    __syncthreads();
#pragma unroll
    for (int kq = 0; kq < 8; ++kq) {        // 4 k-steps per kq, ascending
      float4 xr[8], er[8];
#pragma unroll
      for (int i = 0; i < 8; ++i)
        xr[i] = *reinterpret_cast<const float4*>(&Xs[(rg + 16 * i) * LDP + kq * 4]);
#pragma unroll
      for (int j = 0; j < 8; ++j)
        er[j] = *reinterpret_cast<const float4*>(&Es[(ct + 16 * j) * LDP + kq * 4]);
#pragma unroll
      for (int i = 0; i < 8; ++i)
#pragma unroll
        for (int j = 0; j < 8; ++j) {
          float a = acc[i][j];
          a = __fmaf_rn(xr[i].x, er[j].x, a);   // k ascending xyzw: exact order
          a = __fmaf_rn(xr[i].y, er[j].y, a);
          a = __fmaf_rn(xr[i].z, er[j].z, a);
          a = __fmaf_rn(xr[i].w, er[j].w, a);
          acc[i][j] = a;
        }
    }
    __syncthreads();
  }

  // fused argmin epilogue: per-row lex (s, idx) min -> packed u64 atomicMin
#pragma unroll
  for (int i = 0; i < 8; ++i) {
    int row = R0 + rg + 16 * i;
    float r2v = r2f[row];
    float m = INFINITY; int mi = 0x7fffffff;
#pragma unroll
    for (int j = 0; j < 8; ++j) {           // within-thread cols ascending
      int c = C0 + ct + 16 * j;
      float s = __fsub_rn(__fadd_rn(r2v, e2f[c]), __fmul_rn(2.0f, acc[i][j]));
      if (s < m) { m = s; mi = c; }
    }
#pragma unroll
    for (int off = 1; off < 16; off <<= 1) { // lex reduce across the 16 col-threads
      float os = __shfl_xor(m, off);
      int oi = __shfl_xor(mi, off);
      if (os < m || (os == m && oi < mi)) { m = os; mi = oi; }
    }
    if (ct == 0) {
      unsigned long long key = ((unsigned long long)fmap(m) << 32) | (unsigned)mi;
      atomicMin(&packed[row], key);          // lex-min across col-tiles; tie -> low idx
    }
  }
}

__global__ __launch_bounds__(256) void k_finalize(const unsigned long long* __restrict__ packed,
                                                  int* __restrict__ fidx,
                                                  float* __restrict__ out_idx) {
  int row = blockIdx.x * 256 + threadIdx.x;
  int idx = (int)(unsigned)(packed[row] & 0xFFFFFFFFull);
  fidx[row] = idx;
  out_idx[row] = (float)idx;
}

__global__ __launch_bounds__(256) void k_gather(const float* __restrict__ z,
                                                const float* __restrict__ cb,
                                                const int* __restrict__ fidx,
                                                float* __restrict__ out_q,
                                                double* __restrict__ lpart) {
  __shared__ double red[4];
  int t = threadIdx.x;
  int w = t >> 6, lane = t & 63;
  int row = blockIdx.x * 4 + w;
  int idx = fidx[row];
  float4 q = *reinterpret_cast<const float4*>(cb + (size_t)idx * DDIM + lane * 4);
  float4 x = *reinterpret_cast<const float4*>(z + (size_t)row * DDIM + lane * 4);
  float* o = out_q + (size_t)row * DDIM + lane * 4;  // out+1 base: scalar stores
  o[0] = q.x; o[1] = q.y; o[2] = q.z; o[3] = q.w;
  float dx = q.x - x.x, dy = q.y - x.y, dz = q.z - x.z, dw = q.w - x.w;
  double s = (double)dx * dx + (double)dy * dy + (double)dz * dz + (double)dw * dw;
#pragma unroll
  for (int off = 1; off < 64; off <<= 1) s += __shfl_xor(s, off);
  if (lane == 0) red[w] = s;
  __syncthreads();
  if (t == 0) lpart[blockIdx.x] = (red[0] + red[1]) + (red[2] + red[3]);
}

__global__ __launch_bounds__(256) void k_loss(const double* __restrict__ lpart,
                                              float* __restrict__ out0) {
  __shared__ double red[256];
  int t = threadIdx.x;
  double s = 0.0;
  for (int j = t; j < 2048; j += 256) s += lpart[j];   // fixed order -> deterministic
  red[t] = s;
  __syncthreads();
  for (int off = 128; off > 0; off >>= 1) {
    if (t < off) red[t] += red[t + off];
    __syncthreads();
  }
  if (t == 0) out0[0] = (float)(1.25 * red[0] / (double)((size_t)NROWS * DDIM));
}

extern "C" void kernel_launch(void* const* d_in, const int* in_sizes, int n_in,
                              void* d_out, int out_size, void* d_ws, size_t ws_size,
                              hipStream_t stream) {
  const float* z  = (const float*)d_in[0];   // [16,512,256] flat
  const float* cb = (const float*)d_in[1];   // [8192,256]
  float* out = (float*)d_out;
  char* ws = (char*)d_ws;                    // needs ~180KB (round 2 proved >=2.2MB)

  size_t off = 0;
  unsigned long long* packed = (unsigned long long*)(ws + off); off += NROWS * 8;
  float*  e2f   = (float*)(ws + off);  off += NROWS * 4;
  float*  r2f   = (float*)(ws + off);  off += NROWS * 4;
  int*    fidx  = (int*)(ws + off);    off += NROWS * 4;
  double* lpart = (double*)(ws + off); off += 2048 * 8;

  float* out_q   = out + 1;
  float* out_idx = out + 1 + (size_t)NROWS * DDIM;

  hipMemsetAsync(packed, 0xFF, NROWS * 8, stream);

  k_prep    <<<(2 * NROWS) / 4, 256, 0, stream>>>(z, cb, r2f, e2f);
  k_exact   <<<64 * 64,         256, 0, stream>>>(z, cb, r2f, e2f, packed);
  k_finalize<<<NROWS / 256,     256, 0, stream>>>(packed, fidx, out_idx);
  k_gather  <<<NROWS / 4,       256, 0, stream>>>(z, cb, fidx, out_q, lpart);
  k_loss    <<<1,               256, 0, stream>>>(lpart, out);
}

// Round 6
// 270.497 us; speedup vs baseline: 99.7113x; 1.8234x over previous
//
#include <hip/hip_runtime.h>
#include <hip/hip_bf16.h>
#include <math.h>

// VQ quantizer: bf16-MFMA prefilter (2 passes) + fp32-chain-exact rescore.
//   Exact semantics (validated rounds 2/4): dist = fl32(fl32(r2+e2) - 2*fma_chain(x.e)),
//   argmin first-min-wins.
// MARGIN math (round-5 post-mortem): score Gumbel tail scale beta ~= 5.3e-4;
//   E[#candidates within M+2delta] ~= e^{(M+2d)/beta}. M=8e-4, 2delta<=3.6e-4 -> ~10
//   expected, CAP=56 -> overflow P ~ 1e-24/row. If cnt>CAP anyway: exact full-scan
//   fallback (deterministic, correct regardless).
// Outputs (float32 flat): [loss | quantized(8192*256) | indices(8192 as float)]

#define NROWS 8192
#define DDIM  256
#define KCW   8192
#define CAP   56
#define MARGIN 8e-4f

typedef __attribute__((ext_vector_type(8))) short short8;
typedef __attribute__((ext_vector_type(4))) float f32x4;

__device__ inline unsigned fmap(float f) {
  unsigned b = __float_as_uint(f);
  return (b & 0x80000000u) ? ~b : (b | 0x80000000u);
}
__device__ inline float funmap(unsigned u) {
  unsigned b = (u & 0x80000000u) ? (u & 0x7FFFFFFFu) : ~u;
  return __uint_as_float(b);
}

__global__ __launch_bounds__(256) void k_cast(const float* __restrict__ z,
                                              const float* __restrict__ cb,
                                              ushort* __restrict__ zb,
                                              ushort* __restrict__ cbb) {
  const size_t half = (size_t)NROWS * DDIM;
  size_t i = ((size_t)blockIdx.x * 256 + threadIdx.x) * 4;
  const float* src = (i < half) ? (z + i) : (cb + (i - half));
  ushort* dst = (i < half) ? (zb + i) : (cbb + (i - half));
  float4 v = *reinterpret_cast<const float4*>(src);
  ushort4 o;
  __hip_bfloat16 bx = __float2bfloat16(v.x); o.x = *(ushort*)&bx;
  __hip_bfloat16 by = __float2bfloat16(v.y); o.y = *(ushort*)&by;
  __hip_bfloat16 bz = __float2bfloat16(v.z); o.z = *(ushort*)&bz;
  __hip_bfloat16 bw = __float2bfloat16(v.w); o.w = *(ushort*)&bw;
  *reinterpret_cast<ushort4*>(dst) = o;
}

__global__ __launch_bounds__(256) void k_prep(const float* __restrict__ z,
                                              const float* __restrict__ cb,
                                              float* __restrict__ r2f,
                                              float* __restrict__ e2f) {
  int t = threadIdx.x, w = t >> 6, lane = t & 63;
  int wid = blockIdx.x * 4 + w;  // 0..16383: first 8192 z rows, rest cb rows
  const float* src = (wid < NROWS) ? (z + (size_t)wid * DDIM)
                                   : (cb + (size_t)(wid - NROWS) * DDIM);
  float4 v = *reinterpret_cast<const float4*>(src + lane * 4);
  double d = (double)v.x * v.x + (double)v.y * v.y + (double)v.z * v.z + (double)v.w * v.w;
#pragma unroll
  for (int off = 1; off < 64; off <<= 1) d += __shfl_xor(d, off);
  if (lane == 0) {
    if (wid < NROWS) r2f[wid] = (float)d;
    else             e2f[wid - NROWS] = (float)d;
  }
}

// 128x128 tile MFMA GEMM over K=256 (BK=64), 4 waves each 64x64.
// LDS tiles XOR-swizzled (T2: byte ^= (row&7)<<4), both write and read sides.
// PHASE 1: per-row min -> atomicMin(rowMinU, fmap(s))
// PHASE 2: collect cols with s <= rowmin + MARGIN (bitwise-identical s via _rn intrinsics)
template<int PHASE>
__global__ __launch_bounds__(256) void k_score(const ushort* __restrict__ zb,
                                               const ushort* __restrict__ cbb,
                                               const float* __restrict__ e2f,
                                               unsigned* __restrict__ rowMinU,
                                               unsigned* __restrict__ cnt,
                                               int* __restrict__ cand) {
  __shared__ ushort Ab[128 * 64];
  __shared__ ushort Bb[128 * 64];
  int t = threadIdx.x, w = t >> 6, lane = t & 63;
  int wg = ((blockIdx.x & 7) << 9) | (blockIdx.x >> 3);   // XCD swizzle (4096%8==0)
  int mt = wg >> 6, nt = wg & 63;
  int wm = w >> 1, wn = w & 1;
  int cl = lane & 15, g = lane >> 4;

  f32x4 acc[4][4];
#pragma unroll
  for (int m = 0; m < 4; ++m)
#pragma unroll
    for (int n = 0; n < 4; ++n) acc[m][n] = (f32x4){0.f, 0.f, 0.f, 0.f};

  for (int ks = 0; ks < 4; ++ks) {
#pragma unroll
    for (int q = 0; q < 4; ++q) {     // stage 16KB A + 16KB B, swizzled writes
      int id = q * 256 + t;           // 0..1023
      int row = id >> 3, c8 = id & 7;
      int sw = (row * 128 + c8 * 16) ^ ((row & 7) << 4);
      *reinterpret_cast<float4*>((char*)Ab + sw) =
          *reinterpret_cast<const float4*>(&zb[((size_t)(mt * 128 + row)) * 256 + ks * 64 + c8 * 8]);
      *reinterpret_cast<float4*>((char*)Bb + sw) =
          *reinterpret_cast<const float4*>(&cbb[((size_t)(nt * 128 + row)) * 256 + ks * 64 + c8 * 8]);
    }
    __syncthreads();
#pragma unroll
    for (int kk = 0; kk < 2; ++kk) {
      short8 af[4], bf[4];
#pragma unroll
      for (int m = 0; m < 4; ++m) {
        int arow = wm * 64 + m * 16 + cl;
        int ab = (arow * 128 + kk * 64 + g * 16) ^ ((arow & 7) << 4);
        af[m] = *reinterpret_cast<const short8*>((char*)Ab + ab);
      }
#pragma unroll
      for (int n = 0; n < 4; ++n) {
        int brow = wn * 64 + n * 16 + cl;
        int bb = (brow * 128 + kk * 64 + g * 16) ^ ((brow & 7) << 4);
        bf[n] = *reinterpret_cast<const short8*>((char*)Bb + bb);
      }
#pragma unroll
      for (int m = 0; m < 4; ++m)
#pragma unroll
        for (int n = 0; n < 4; ++n)
          acc[m][n] = __builtin_amdgcn_mfma_f32_16x16x32_bf16(af[m], bf[n], acc[m][n], 0, 0, 0);
    }
    __syncthreads();
  }

  // epilogue: C/D layout col=lane&15, row=(lane>>4)*4+j  [m89/m91]
  int col_base = nt * 128 + wn * 64;
  int row_base = mt * 128 + wm * 64;
  float e2v[4];
#pragma unroll
  for (int n = 0; n < 4; ++n) e2v[n] = e2f[col_base + n * 16 + cl];

#pragma unroll
  for (int m = 0; m < 4; ++m) {
#pragma unroll
    for (int j = 0; j < 4; ++j) {
      int row = row_base + m * 16 + g * 4 + j;
      if (PHASE == 1) {
        float mn = INFINITY;
#pragma unroll
        for (int n = 0; n < 4; ++n) {
          float s = __fsub_rn(e2v[n], __fmul_rn(2.0f, acc[m][n][j]));
          mn = fminf(mn, s);
        }
#pragma unroll
        for (int off = 1; off < 16; off <<= 1)
          mn = fminf(mn, __shfl_xor(mn, off));
        if (cl == 0) atomicMin(&rowMinU[row], fmap(mn));
      } else {
        float thr = funmap(rowMinU[row]) + MARGIN;
#pragma unroll
        for (int n = 0; n < 4; ++n) {
          float s = __fsub_rn(e2v[n], __fmul_rn(2.0f, acc[m][n][j]));
          if (s <= thr) {
            unsigned slot = atomicAdd(&cnt[row], 1u);
            if (slot < CAP) cand[row * CAP + slot] = col_base + n * 16 + cl;
          }
        }
      }
    }
  }
}

// Exact fp32-chain rescore; lexicographic (s, idx) min = first-min-wins.
// cnt>CAP (never expected): full exact scan fallback — deterministic & correct.
__global__ __launch_bounds__(256) void k_rescore(const float* __restrict__ z,
                                                 const float* __restrict__ cb,
                                                 const float* __restrict__ r2f,
                                                 const float* __restrict__ e2f,
                                                 const unsigned* __restrict__ cnt,
                                                 const int* __restrict__ cand,
                                                 int* __restrict__ fidx,
                                                 float* __restrict__ out_idx) {
  int t = threadIdx.x, w = t >> 6, lane = t & 63;
  int row = blockIdx.x * 4 + w;
  unsigned n = cnt[row];
  float s = INFINITY; int ci = 0x7fffffff;
  const float* xp = z + (size_t)row * DDIM;
  float r2v = r2f[row];
  if (n <= CAP) {
    if (lane < (int)n) {
      ci = cand[row * CAP + lane];
      const float* ep = cb + (size_t)ci * DDIM;
      float acc = 0.f;
      for (int k = 0; k < DDIM; ++k) acc = __fmaf_rn(xp[k], ep[k], acc);  // k ascending
      s = __fsub_rn(__fadd_rn(r2v, e2f[ci]), __fmul_rn(2.0f, acc));
    }
  } else {
    // overflow fallback: exact scan of all K candidates (lane c, c+64, ...)
    for (int base = 0; base < KCW; base += 64) {
      int c = base + lane;
      const float* ep = cb + (size_t)c * DDIM;
      float acc = 0.f;
      for (int k = 0; k < DDIM; ++k) acc = __fmaf_rn(xp[k], ep[k], acc);
      float sc = __fsub_rn(__fadd_rn(r2v, e2f[c]), __fmul_rn(2.0f, acc));
      if (sc < s) { s = sc; ci = c; }          // c ascending per lane: first-wins
    }
  }
#pragma unroll
  for (int off = 1; off < 64; off <<= 1) {
    float os = __shfl_xor(s, off); int oi = __shfl_xor(ci, off);
    if (os < s || (os == s && oi < ci)) { s = os; ci = oi; }
  }
  if (lane == 0) { fidx[row] = ci; out_idx[row] = (float)ci; }
}

__global__ __launch_bounds__(256) void k_gather(const float* __restrict__ z,
                                                const float* __restrict__ cb,
                                                const int* __restrict__ fidx,
                                                float* __restrict__ out_q,
                                                double* __restrict__ lpart) {
  __shared__ double red[4];
  int t = threadIdx.x;
  int w = t >> 6, lane = t & 63;
  int row = blockIdx.x * 4 + w;
  int idx = fidx[row];
  float4 q = *reinterpret_cast<const float4*>(cb + (size_t)idx * DDIM + lane * 4);
  float4 x = *reinterpret_cast<const float4*>(z + (size_t)row * DDIM + lane * 4);
  float* o = out_q + (size_t)row * DDIM + lane * 4;  // out+1 base: scalar stores
  o[0] = q.x; o[1] = q.y; o[2] = q.z; o[3] = q.w;
  float dx = q.x - x.x, dy = q.y - x.y, dz = q.z - x.z, dw = q.w - x.w;
  double s = (double)dx * dx + (double)dy * dy + (double)dz * dz + (double)dw * dw;
#pragma unroll
  for (int off = 1; off < 64; off <<= 1) s += __shfl_xor(s, off);
  if (lane == 0) red[w] = s;
  __syncthreads();
  if (t == 0) lpart[blockIdx.x] = (red[0] + red[1]) + (red[2] + red[3]);
}

__global__ __launch_bounds__(256) void k_loss(const double* __restrict__ lpart,
                                              float* __restrict__ out0) {
  __shared__ double red[256];
  int t = threadIdx.x;
  double s = 0.0;
  for (int j = t; j < 2048; j += 256) s += lpart[j];   // fixed order -> deterministic
  red[t] = s;
  __syncthreads();
  for (int off = 128; off > 0; off >>= 1) {
    if (t < off) red[t] += red[t + off];
    __syncthreads();
  }
  if (t == 0) out0[0] = (float)(1.25 * red[0] / (double)((size_t)NROWS * DDIM));
}

extern "C" void kernel_launch(void* const* d_in, const int* in_sizes, int n_in,
                              void* d_out, int out_size, void* d_ws, size_t ws_size,
                              hipStream_t stream) {
  const float* z  = (const float*)d_in[0];   // [16,512,256] flat
  const float* cb = (const float*)d_in[1];   // [8192,256]
  float* out = (float*)d_out;
  char* ws = (char*)d_ws;
  const size_t HALF = (size_t)NROWS * DDIM;  // 2,097,152

  // bf16 copies in the out_q region (out+4 floats: 16B-aligned; spans exactly
  // 2*HALF ushorts -> last 3 floats overlap out_idx[0..2], which is written
  // AFTER the last zb/cbb read (k_score<2>) by k_rescore. Recomputed every call.
  ushort* zb  = (ushort*)(out + 4);
  ushort* cbb = zb + HALF;

  // ws total: 5*32KB + 16KB + 8192*56*4 = 2,015,232 B (< 2.21MB proven in round 2)
  size_t off = 0;
  float*    e2f     = (float*)(ws + off);    off += NROWS * 4;
  float*    r2f     = (float*)(ws + off);    off += NROWS * 4;
  unsigned* rowMinU = (unsigned*)(ws + off); off += NROWS * 4;
  unsigned* cnt     = (unsigned*)(ws + off); off += NROWS * 4;
  int*      fidx    = (int*)(ws + off);      off += NROWS * 4;
  double*   lpart   = (double*)(ws + off);   off += 2048 * 8;
  int*      cand    = (int*)(ws + off);      off += (size_t)NROWS * CAP * 4;

  float* out_q   = out + 1;
  float* out_idx = out + 1 + HALF;

  hipMemsetAsync(rowMinU, 0xFF, NROWS * 4, stream);
  hipMemsetAsync(cnt, 0, NROWS * 4, stream);

  k_cast    <<<(2 * HALF) / 1024, 256, 0, stream>>>(z, cb, zb, cbb);
  k_prep    <<<(2 * NROWS) / 4,   256, 0, stream>>>(z, cb, r2f, e2f);
  k_score<1><<<64 * 64,           256, 0, stream>>>(zb, cbb, e2f, rowMinU, cnt, cand);
  k_score<2><<<64 * 64,           256, 0, stream>>>(zb, cbb, e2f, rowMinU, cnt, cand);
  k_rescore <<<NROWS / 4,         256, 0, stream>>>(z, cb, r2f, e2f, cnt, cand, fidx, out_idx);
  k_gather  <<<NROWS / 4,         256, 0, stream>>>(z, cb, fidx, out_q, lpart);
  k_loss    <<<1,                 256, 0, stream>>>(lpart, out);
}

// Round 7
// 217.624 us; speedup vs baseline: 123.9368x; 1.2430x over previous
//
#include <hip/hip_runtime.h>
#include <hip/hip_bf16.h>
#include <math.h>

// VQ quantizer: bf16-MFMA prefilter (2 passes) + fp32-chain-exact rescore.
//   Exact semantics (validated r2/r4/r6): dist = fl32(fl32(r2+e2) - 2*fma_chain(x.e)),
//   argmin first-min-wins. MARGIN=8e-4 covers 2*delta_mfma(<=3.6e-4); Gumbel tail
//   beta~5.3e-4 -> E[cands]~10, CAP=56 (overflow P~1e-24; exact full-scan fallback).
// Round 7: global_load_lds width=16 staging (linear LDS dest + inverse-swizzled
//   global source + XOR on ds_read — rule #21), fused prep/cast and rescore/gather.
// Outputs (float32 flat): [loss | quantized(8192*256) | indices(8192 as float)]

#define NROWS 8192
#define DDIM  256
#define KCW   8192
#define CAP   56
#define MARGIN 8e-4f

typedef __attribute__((ext_vector_type(8))) short short8;
typedef __attribute__((ext_vector_type(4))) float f32x4;
typedef unsigned int u32;

__device__ inline void async_copy16(void* lds_uniform, const void* gsrc) {
  __builtin_amdgcn_global_load_lds(
      (const __attribute__((address_space(1))) u32*)gsrc,
      (__attribute__((address_space(3))) u32*)lds_uniform, 16, 0, 0);
}

__device__ inline unsigned fmap(float f) {
  unsigned b = __float_as_uint(f);
  return (b & 0x80000000u) ? ~b : (b | 0x80000000u);
}
__device__ inline float funmap(unsigned u) {
  unsigned b = (u & 0x80000000u) ? (u & 0x7FFFFFFFu) : ~u;
  return __uint_as_float(b);
}

// Fused: bf16 cast + r2/e2 (f64->f32) + workspace init (rowMinU/cnt).
__global__ __launch_bounds__(256) void k_prep_cast(const float* __restrict__ z,
                                                   const float* __restrict__ cb,
                                                   ushort* __restrict__ zb,
                                                   ushort* __restrict__ cbb,
                                                   float* __restrict__ r2f,
                                                   float* __restrict__ e2f,
                                                   unsigned* __restrict__ rowMinU,
                                                   unsigned* __restrict__ cnt) {
  int t = threadIdx.x, w = t >> 6, lane = t & 63;
  int wid = blockIdx.x * 4 + w;           // 0..16383
  bool isCb = wid >= NROWS;
  int row = isCb ? wid - NROWS : wid;
  const float* src = (isCb ? cb : z) + (size_t)row * DDIM + lane * 4;
  float4 v = *reinterpret_cast<const float4*>(src);
  ushort4 o;
  __hip_bfloat16 bx = __float2bfloat16(v.x); o.x = *(ushort*)&bx;
  __hip_bfloat16 by = __float2bfloat16(v.y); o.y = *(ushort*)&by;
  __hip_bfloat16 bz = __float2bfloat16(v.z); o.z = *(ushort*)&bz;
  __hip_bfloat16 bw = __float2bfloat16(v.w); o.w = *(ushort*)&bw;
  ushort* dst = (isCb ? cbb : zb) + (size_t)row * DDIM + lane * 4;
  *reinterpret_cast<ushort4*>(dst) = o;
  double d = (double)v.x * v.x + (double)v.y * v.y + (double)v.z * v.z + (double)v.w * v.w;
#pragma unroll
  for (int off = 1; off < 64; off <<= 1) d += __shfl_xor(d, off);
  if (lane == 0) {
    if (isCb) e2f[row] = (float)d;
    else { r2f[row] = (float)d; rowMinU[row] = ~0u; cnt[row] = 0; }
  }
}

// 128x128 tile MFMA GEMM, BK=64, 4 waves each 64x64.
// Staging: global_load_lds (16B/lane), LINEAR LDS dest; the XOR swizzle
// (slot ^= row&7, 16B slots) is applied to the GLOBAL source address, and the
// identical XOR on the ds_read side (round-6-proven, 0 conflicts).
// PHASE 1: per-row min -> atomicMin(rowMinU, fmap(s))
// PHASE 2: collect cols with s <= rowmin + MARGIN (bitwise-identical s)
template<int PHASE>
__global__ __launch_bounds__(256) void k_score(const ushort* __restrict__ zb,
                                               const ushort* __restrict__ cbb,
                                               const float* __restrict__ e2f,
                                               unsigned* __restrict__ rowMinU,
                                               unsigned* __restrict__ cnt,
                                               int* __restrict__ cand) {
  __shared__ ushort Ab[128 * 64];
  __shared__ ushort Bb[128 * 64];
  int t = threadIdx.x, w = t >> 6, lane = t & 63;
  int wg = ((blockIdx.x & 7) << 9) | (blockIdx.x >> 3);   // XCD swizzle (4096%8==0)
  int mt = wg >> 6, nt = wg & 63;
  int wm = w >> 1, wn = w & 1;
  int cl = lane & 15, g = lane >> 4;

  // staging geometry: 32 chunks of 1KB (16 A, 16 B); wave w owns chunks w*8..w*8+7.
  // lane l in chunk: row_in_chunk = l>>3, slot = l&7 (16B granules of a 128B k-slice);
  // global source slot = (l&7) ^ (l>>3)  [inverse swizzle; row&7 == l>>3]
  int rloc8 = lane >> 3;                 // 0..7
  int sslot = (lane & 7) ^ rloc8;        // pre-swizzled source slot
  const ushort* arow_base = zb  + (size_t)(mt * 128) * DDIM;
  const ushort* brow_base = cbb + (size_t)(nt * 128) * DDIM;

  f32x4 acc[4][4];
#pragma unroll
  for (int m = 0; m < 4; ++m)
#pragma unroll
    for (int n = 0; n < 4; ++n) acc[m][n] = (f32x4){0.f, 0.f, 0.f, 0.f};

  for (int ks = 0; ks < 4; ++ks) {
#pragma unroll
    for (int i = 0; i < 8; ++i) {
      int ch = w * 8 + i;                            // 0..31, uniform per wave
      int ct = ch & 15;                              // tile chunk 0..15
      int row = ct * 8 + rloc8;                      // row within 128-tile
      const ushort* src = (ch < 16)
          ? arow_base + (size_t)row * DDIM + ks * 64 + sslot * 8
          : brow_base + (size_t)row * DDIM + ks * 64 + sslot * 8;
      char* ldsb = (char*)(ch < 16 ? Ab : Bb) + ct * 1024;   // uniform base
      async_copy16(ldsb, src);
    }
    __syncthreads();                                  // drains vmcnt (compiler)
#pragma unroll
    for (int kk = 0; kk < 2; ++kk) {
      short8 af[4], bf[4];
#pragma unroll
      for (int m = 0; m < 4; ++m) {
        int arow = wm * 64 + m * 16 + cl;
        int ab = arow * 128 + (((kk * 4 + g) ^ (arow & 7)) << 4);
        af[m] = *reinterpret_cast<const short8*>((char*)Ab + ab);
      }
#pragma unroll
      for (int n = 0; n < 4; ++n) {
        int brow = wn * 64 + n * 16 + cl;
        int bb = brow * 128 + (((kk * 4 + g) ^ (brow & 7)) << 4);
        bf[n] = *reinterpret_cast<const short8*>((char*)Bb + bb);
      }
#pragma unroll
      for (int m = 0; m < 4; ++m)
#pragma unroll
        for (int n = 0; n < 4; ++n)
          acc[m][n] = __builtin_amdgcn_mfma_f32_16x16x32_bf16(af[m], bf[n], acc[m][n], 0, 0, 0);
    }
    __syncthreads();
  }

  // epilogue: C/D layout col=lane&15, row=(lane>>4)*4+j  [m89/m91]
  int col_base = nt * 128 + wn * 64;
  int row_base = mt * 128 + wm * 64;
  float e2v[4];
#pragma unroll
  for (int n = 0; n < 4; ++n) e2v[n] = e2f[col_base + n * 16 + cl];

#pragma unroll
  for (int m = 0; m < 4; ++m) {
#pragma unroll
    for (int j = 0; j < 4; ++j) {
      int row = row_base + m * 16 + g * 4 + j;
      if (PHASE == 1) {
        float mn = INFINITY;
#pragma unroll
        for (int n = 0; n < 4; ++n) {
          float s = __fsub_rn(e2v[n], __fmul_rn(2.0f, acc[m][n][j]));
          mn = fminf(mn, s);
        }
#pragma unroll
        for (int off = 1; off < 16; off <<= 1)
          mn = fminf(mn, __shfl_xor(mn, off));
        if (cl == 0) atomicMin(&rowMinU[row], fmap(mn));
      } else {
        float thr = funmap(rowMinU[row]) + MARGIN;
#pragma unroll
        for (int n = 0; n < 4; ++n) {
          float s = __fsub_rn(e2v[n], __fmul_rn(2.0f, acc[m][n][j]));
          if (s <= thr) {
            unsigned slot = atomicAdd(&cnt[row], 1u);
            if (slot < CAP) cand[row * CAP + slot] = col_base + n * 16 + cl;
          }
        }
      }
    }
  }
}

// Fused: exact fp32-chain rescore (lex (s,idx) min = first-min-wins) + overflow
// fallback + gather + per-row loss partial.
__global__ __launch_bounds__(256) void k_rescore_gather(const float* __restrict__ z,
                                                        const float* __restrict__ cb,
                                                        const float* __restrict__ r2f,
                                                        const float* __restrict__ e2f,
                                                        const unsigned* __restrict__ cnt,
                                                        const int* __restrict__ cand,
                                                        float* __restrict__ out_q,
                                                        float* __restrict__ out_idx,
                                                        double* __restrict__ lpart) {
  int t = threadIdx.x, w = t >> 6, lane = t & 63;
  int row = blockIdx.x * 4 + w;
  unsigned n = cnt[row];
  float s = INFINITY; int ci = 0x7fffffff;
  const float* xp = z + (size_t)row * DDIM;
  float r2v = r2f[row];
  if (n <= CAP) {
    if (lane < (int)n) {
      ci = cand[row * CAP + lane];
      const float* ep = cb + (size_t)ci * DDIM;
      float acc = 0.f;
      for (int k = 0; k < DDIM; ++k) acc = __fmaf_rn(xp[k], ep[k], acc);  // k ascending
      s = __fsub_rn(__fadd_rn(r2v, e2f[ci]), __fmul_rn(2.0f, acc));
    }
  } else {
    for (int base = 0; base < KCW; base += 64) {      // exact full-scan fallback
      int c = base + lane;
      const float* ep = cb + (size_t)c * DDIM;
      float acc = 0.f;
      for (int k = 0; k < DDIM; ++k) acc = __fmaf_rn(xp[k], ep[k], acc);
      float sc = __fsub_rn(__fadd_rn(r2v, e2f[c]), __fmul_rn(2.0f, acc));
      if (sc < s) { s = sc; ci = c; }
    }
  }
#pragma unroll
  for (int off = 1; off < 64; off <<= 1) {            // butterfly: ALL lanes get min
    float os = __shfl_xor(s, off); int oi = __shfl_xor(ci, off);
    if (os < s || (os == s && oi < ci)) { s = os; ci = oi; }
  }
  if (lane == 0) out_idx[row] = (float)ci;

  // gather + loss partial
  float4 q = *reinterpret_cast<const float4*>(cb + (size_t)ci * DDIM + lane * 4);
  float4 x = *reinterpret_cast<const float4*>(xp + lane * 4);
  float* o = out_q + (size_t)row * DDIM + lane * 4;   // out+1 base: scalar stores
  o[0] = q.x; o[1] = q.y; o[2] = q.z; o[3] = q.w;
  float dx = q.x - x.x, dy = q.y - x.y, dz = q.z - x.z, dw = q.w - x.w;
  double d = (double)dx * dx + (double)dy * dy + (double)dz * dz + (double)dw * dw;
#pragma unroll
  for (int off = 1; off < 64; off <<= 1) d += __shfl_xor(d, off);
  if (lane == 0) lpart[row] = d;
}

__global__ __launch_bounds__(256) void k_loss(const double* __restrict__ lpart,
                                              float* __restrict__ out0) {
  __shared__ double red[256];
  int t = threadIdx.x;
  double s = 0.0;
  for (int j = t; j < NROWS; j += 256) s += lpart[j];  // fixed order -> deterministic
  red[t] = s;
  __syncthreads();
  for (int off = 128; off > 0; off >>= 1) {
    if (t < off) red[t] += red[t + off];
    __syncthreads();
  }
  if (t == 0) out0[0] = (float)(1.25 * red[0] / (double)((size_t)NROWS * DDIM));
}

extern "C" void kernel_launch(void* const* d_in, const int* in_sizes, int n_in,
                              void* d_out, int out_size, void* d_ws, size_t ws_size,
                              hipStream_t stream) {
  const float* z  = (const float*)d_in[0];   // [16,512,256] flat
  const float* cb = (const float*)d_in[1];   // [8192,256]
  float* out = (float*)d_out;
  char* ws = (char*)d_ws;
  const size_t HALF = (size_t)NROWS * DDIM;  // 2,097,152

  // bf16 copies in the out_q region (out+4 floats: 16B-aligned). Last 3 floats
  // of cbb overlap out_idx[0..2]; out_idx is written by k_rescore_gather, which
  // runs after the last zb/cbb read (k_score<2>). Recomputed every call.
  ushort* zb  = (ushort*)(out + 4);
  ushort* cbb = zb + HALF;

  // ws total: 4*32KB + 64KB + 8192*56*4 = 2,027,520 B (< 2.21MB proven in r2)
  size_t off = 0;
  float*    e2f     = (float*)(ws + off);    off += NROWS * 4;
  float*    r2f     = (float*)(ws + off);    off += NROWS * 4;
  unsigned* rowMinU = (unsigned*)(ws + off); off += NROWS * 4;
  unsigned* cnt     = (unsigned*)(ws + off); off += NROWS * 4;
  double*   lpart   = (double*)(ws + off);   off += NROWS * 8;
  int*      cand    = (int*)(ws + off);      off += (size_t)NROWS * CAP * 4;

  float* out_q   = out + 1;
  float* out_idx = out + 1 + HALF;

  k_prep_cast     <<<(2 * NROWS) / 4, 256, 0, stream>>>(z, cb, zb, cbb, r2f, e2f, rowMinU, cnt);
  k_score<1>      <<<64 * 64,         256, 0, stream>>>(zb, cbb, e2f, rowMinU, cnt, cand);
  k_score<2>      <<<64 * 64,         256, 0, stream>>>(zb, cbb, e2f, rowMinU, cnt, cand);
  k_rescore_gather<<<NROWS / 4,       256, 0, stream>>>(z, cb, r2f, e2f, cnt, cand, out_q, out_idx, lpart);
  k_loss          <<<1,               256, 0, stream>>>(lpart, out);
}